// Round 1
// baseline (1236.618 us; speedup 1.0000x reference)
//
#include <hip/hip_runtime.h>
#include <math.h>

#define NPTS 4096
#define DIM 64
#define NM ((size_t)NPTS * (size_t)NPTS)
#define LOGW (-8.317766166719343f)   // -log(4096)
#define NEGINF (-__builtin_inff())

// ---------------------------------------------------------------------------
// Normalize rows of x and y to unit L2 norm. One wave (64 lanes) per row.
// grid 2048 x 256 threads: 8192 rows total (x then y).
// ---------------------------------------------------------------------------
__global__ __launch_bounds__(256) void norm_kernel(
    const float* __restrict__ x, const float* __restrict__ y,
    float* __restrict__ xn, float* __restrict__ yn) {
  int row  = blockIdx.x * 4 + (threadIdx.x >> 6);
  int lane = threadIdx.x & 63;
  const float* src;
  float* dst;
  if (row < NPTS) { src = x + (size_t)row * DIM;          dst = xn + (size_t)row * DIM; }
  else            { src = y + (size_t)(row - NPTS) * DIM; dst = yn + (size_t)(row - NPTS) * DIM; }
  float v = src[lane];
  float s = v * v;
  #pragma unroll
  for (int o = 32; o; o >>= 1) s += __shfl_xor(s, o, 64);
  dst[lane] = v * (1.0f / sqrtf(s));
}

// ---------------------------------------------------------------------------
// Cost matrices: C[i][j] = max(1 - dot(A_i, B_j), 0)  (unit-norm rows).
// blockIdx.z: 0 -> C_xy (xn,yn), 1 -> C_xx (xn,xn), 2 -> C_yy (yn,yn).
// 64x64 output tile per block, 256 threads, each computes 4x4.
// ---------------------------------------------------------------------------
__global__ __launch_bounds__(256) void cost_kernel(
    const float* __restrict__ xn, const float* __restrict__ yn,
    float* __restrict__ ws) {
  int mat = blockIdx.z;
  const float* A = (mat == 2) ? yn : xn;
  const float* B = (mat == 1) ? xn : yn;
  float* Cout = ws + (size_t)mat * NM;

  __shared__ float As[64][68];   // +4 float pad keeps float4 align, breaks banks
  __shared__ float Bs[64][68];

  int tid = threadIdx.x;
  int i0 = blockIdx.y * 64, j0 = blockIdx.x * 64;
  #pragma unroll
  for (int it = 0; it < 4; ++it) {
    int idx = tid + it * 256;            // 0..1023
    int r = idx >> 4, kq = (idx & 15) * 4;
    float4 av = *(const float4*)&A[(size_t)(i0 + r) * DIM + kq];
    *(float4*)&As[r][kq] = av;
    float4 bv = *(const float4*)&B[(size_t)(j0 + r) * DIM + kq];
    *(float4*)&Bs[r][kq] = bv;
  }
  __syncthreads();

  int tx = tid & 15, ty = tid >> 4;      // rows: 4*ty+u ; cols: tx + 16*v
  float acc[4][4] = {};
  #pragma unroll
  for (int k4 = 0; k4 < 16; ++k4) {
    float4 a[4], b[4];
    #pragma unroll
    for (int u = 0; u < 4; ++u) a[u] = *(const float4*)&As[ty * 4 + u][k4 * 4];
    #pragma unroll
    for (int v = 0; v < 4; ++v) b[v] = *(const float4*)&Bs[tx + 16 * v][k4 * 4];
    #pragma unroll
    for (int u = 0; u < 4; ++u)
      #pragma unroll
      for (int v = 0; v < 4; ++v)
        acc[u][v] += a[u].x * b[v].x + a[u].y * b[v].y +
                     a[u].z * b[v].z + a[u].w * b[v].w;
  }
  #pragma unroll
  for (int u = 0; u < 4; ++u)
    #pragma unroll
    for (int v = 0; v < 4; ++v)
      Cout[(size_t)(i0 + ty * 4 + u) * NPTS + (j0 + tx + 16 * v)] =
          fmaxf(1.0f - acc[u][v], 0.0f);
}

// ---------------------------------------------------------------------------
// One sweep: 3 row-softmins (C_xy->ft_ba, C_xx->ft_aa, C_yy->gt_bb) and the
// column-softmin over C_xy (partials pm/ps, 32 chunks of 128 rows).
// Blocks 0..3071: row pass (wave per row). Blocks 3072..3327: column pass.
// Online max-shifted logsumexp:  t = h - C/eps ;  track (m, s).
// ---------------------------------------------------------------------------
__global__ __launch_bounds__(256) void pass_kernel(
    const float* __restrict__ Cw,
    const float* __restrict__ f_ba, const float* __restrict__ g_ab,
    const float* __restrict__ f_aa, const float* __restrict__ g_bb,
    float* __restrict__ ft_ba, float* __restrict__ ft_aa,
    float* __restrict__ gt_bb,
    float* __restrict__ pm, float* __restrict__ ps,
    float inv_eps, float eps, int use_pot) {
  int blk = blockIdx.x;
  if (blk < 3072) {
    // ---- row pass ----
    int mat   = blk >> 10;
    int local = blk & 1023;
    int row   = local * 4 + (threadIdx.x >> 6);
    int lane  = threadIdx.x & 63;
    const float* Cb  = Cw + (size_t)mat * NM + (size_t)row * NPTS;
    const float* pot = (mat == 0) ? g_ab : ((mat == 1) ? f_aa : g_bb);
    float* outp      = (mat == 0) ? ft_ba : ((mat == 1) ? ft_aa : gt_bb);

    float m = NEGINF, s = 0.0f;
    #pragma unroll 4
    for (int t = 0; t < 16; ++t) {
      int j = lane * 4 + t * 256;
      float4 c4 = *(const float4*)&Cb[j];
      float4 h4;
      if (use_pot) {
        float4 p4 = *(const float4*)&pot[j];
        h4.x = fmaf(p4.x, inv_eps, LOGW);
        h4.y = fmaf(p4.y, inv_eps, LOGW);
        h4.z = fmaf(p4.z, inv_eps, LOGW);
        h4.w = fmaf(p4.w, inv_eps, LOGW);
      } else {
        h4.x = h4.y = h4.z = h4.w = LOGW;
      }
      float tv, mn;
      tv = fmaf(c4.x, -inv_eps, h4.x); mn = fmaxf(m, tv);
      s = s * __expf(m - mn) + __expf(tv - mn); m = mn;
      tv = fmaf(c4.y, -inv_eps, h4.y); mn = fmaxf(m, tv);
      s = s * __expf(m - mn) + __expf(tv - mn); m = mn;
      tv = fmaf(c4.z, -inv_eps, h4.z); mn = fmaxf(m, tv);
      s = s * __expf(m - mn) + __expf(tv - mn); m = mn;
      tv = fmaf(c4.w, -inv_eps, h4.w); mn = fmaxf(m, tv);
      s = s * __expf(m - mn) + __expf(tv - mn); m = mn;
    }
    // wave merge of (m, s)
    #pragma unroll
    for (int o = 1; o < 64; o <<= 1) {
      float m2 = __shfl_xor(m, o, 64);
      float s2 = __shfl_xor(s, o, 64);
      float mn = fmaxf(m, m2);
      s = s * __expf(m - mn) + s2 * __expf(m2 - mn);
      m = mn;
    }
    if (lane == 0) outp[row] = -eps * (m + __logf(s));
  } else {
    // ---- column pass over C_xy: h[i] = LOGW + f_ba[i]/eps ----
    int cb = blk - 3072;
    int cg = cb & 7;          // 8 column groups of 512
    int ch = cb >> 3;         // 32 row chunks of 128
    int j  = cg * 512 + threadIdx.x * 2;
    int i0 = ch * 128;
    float m0 = NEGINF, s0 = 0.0f, m1 = NEGINF, s1 = 0.0f;
    #pragma unroll 4
    for (int r = 0; r < 128; ++r) {
      int i = i0 + r;
      float2 c2 = *(const float2*)&Cw[(size_t)i * NPTS + j];
      float h = use_pot ? fmaf(f_ba[i], inv_eps, LOGW) : LOGW;
      float tv, mn;
      tv = fmaf(c2.x, -inv_eps, h); mn = fmaxf(m0, tv);
      s0 = s0 * __expf(m0 - mn) + __expf(tv - mn); m0 = mn;
      tv = fmaf(c2.y, -inv_eps, h); mn = fmaxf(m1, tv);
      s1 = s1 * __expf(m1 - mn) + __expf(tv - mn); m1 = mn;
    }
    pm[(size_t)ch * NPTS + j]     = m0;
    pm[(size_t)ch * NPTS + j + 1] = m1;
    ps[(size_t)ch * NPTS + j]     = s0;
    ps[(size_t)ch * NPTS + j + 1] = s1;
  }
}

// ---------------------------------------------------------------------------
// Combine column partials -> gt_ab, then update all four potentials.
// avg=1: f = 0.5*(f + ft)   avg=0: f = ft (init and final extrapolation).
// grid 32 x 128 threads (one thread per column/row index).
// ---------------------------------------------------------------------------
__global__ __launch_bounds__(128) void update_kernel(
    float* __restrict__ f_ba, float* __restrict__ g_ab,
    float* __restrict__ f_aa, float* __restrict__ g_bb,
    const float* __restrict__ ft_ba, const float* __restrict__ ft_aa,
    const float* __restrict__ gt_bb,
    const float* __restrict__ pm, const float* __restrict__ ps,
    float eps, int avg) {
  int j = blockIdx.x * 128 + threadIdx.x;
  float m = NEGINF, s = 0.0f;
  #pragma unroll
  for (int c = 0; c < 32; ++c) {
    float m2 = pm[(size_t)c * NPTS + j];
    float s2 = ps[(size_t)c * NPTS + j];
    float mn = fmaxf(m, m2);
    s = s * __expf(m - mn) + s2 * __expf(m2 - mn);
    m = mn;
  }
  float gt = -eps * (m + __logf(s));
  if (avg) {
    g_ab[j] = 0.5f * (g_ab[j] + gt);
    f_ba[j] = 0.5f * (f_ba[j] + ft_ba[j]);
    f_aa[j] = 0.5f * (f_aa[j] + ft_aa[j]);
    g_bb[j] = 0.5f * (g_bb[j] + gt_bb[j]);
  } else {
    g_ab[j] = gt;
    f_ba[j] = ft_ba[j];
    f_aa[j] = ft_aa[j];
    g_bb[j] = gt_bb[j];
  }
}

// ---------------------------------------------------------------------------
// out = mean(f_ba - f_aa) + mean(g_ab - g_bb)
// ---------------------------------------------------------------------------
__global__ __launch_bounds__(256) void final_kernel(
    const float* __restrict__ f_ba, const float* __restrict__ g_ab,
    const float* __restrict__ f_aa, const float* __restrict__ g_bb,
    float* __restrict__ out) {
  __shared__ float red[256];
  float s = 0.0f;
  for (int j = threadIdx.x; j < NPTS; j += 256)
    s += (f_ba[j] - f_aa[j]) + (g_ab[j] - g_bb[j]);
  red[threadIdx.x] = s;
  __syncthreads();
  #pragma unroll
  for (int o = 128; o; o >>= 1) {
    if (threadIdx.x < o) red[threadIdx.x] += red[threadIdx.x + o];
    __syncthreads();
  }
  if (threadIdx.x == 0) out[0] = red[0] / (float)NPTS;
}

extern "C" void kernel_launch(void* const* d_in, const int* in_sizes, int n_in,
                              void* d_out, int out_size, void* d_ws, size_t ws_size,
                              hipStream_t stream) {
  const float* x = (const float*)d_in[0];
  const float* y = (const float*)d_in[1];
  float* ws = (float*)d_ws;

  // workspace layout (floats)
  float* Cw    = ws;                         // 3 * NM
  float* xn    = ws + 3 * NM;                // 4096*64
  float* yn    = xn + (size_t)NPTS * DIM;
  float* f_ba  = yn + (size_t)NPTS * DIM;
  float* g_ab  = f_ba + NPTS;
  float* f_aa  = g_ab + NPTS;
  float* g_bb  = f_aa + NPTS;
  float* ft_ba = g_bb + NPTS;
  float* ft_aa = ft_ba + NPTS;
  float* gt_bb = ft_aa + NPTS;
  float* pm    = gt_bb + NPTS;               // 32 * 4096
  float* ps    = pm + 32 * (size_t)NPTS;     // 32 * 4096
  size_t needed = (size_t)(ps + 32 * (size_t)NPTS - ws) * sizeof(float);
  if (ws_size < needed) return;  // workspace too small; fail visibly

  norm_kernel<<<2048, 256, 0, stream>>>(x, y, xn, yn);
  cost_kernel<<<dim3(64, 64, 3), 256, 0, stream>>>(xn, yn, Cw);

  // geomloss epsilon schedule (p=2, blur=0.05, scaling=0.8, diameter=2)
  double lst[32];
  int c = 0;
  lst[c++] = 4.0;
  double start = 2.0 * log(2.0), stop = 2.0 * log(0.05), step = 2.0 * log(0.8);
  for (int k = 0;; ++k) {
    double v = start + (double)k * step;
    if (v <= stop) break;
    lst[c++] = exp(v);
  }
  lst[c++] = 0.05 * 0.05;     // c == 19

  // pairs: 0 = init (no pot, assign); 1..c = loop (avg); c+1 = final (assign)
  for (int p = 0; p < c + 2; ++p) {
    double e = (p == 0) ? lst[0] : ((p <= c) ? lst[p - 1] : lst[c - 1]);
    float eps = (float)e;
    float inv_eps = 1.0f / eps;
    int use_pot = (p > 0) ? 1 : 0;
    int avg = (p >= 1 && p <= c) ? 1 : 0;
    pass_kernel<<<3072 + 256, 256, 0, stream>>>(
        Cw, f_ba, g_ab, f_aa, g_bb, ft_ba, ft_aa, gt_bb, pm, ps,
        inv_eps, eps, use_pot);
    update_kernel<<<32, 128, 0, stream>>>(
        f_ba, g_ab, f_aa, g_bb, ft_ba, ft_aa, gt_bb, pm, ps, eps, avg);
  }

  final_kernel<<<1, 256, 0, stream>>>(f_ba, g_ab, f_aa, g_bb, (float*)d_out);
}

// Round 2
// 818.071 us; speedup vs baseline: 1.5116x; 1.5116x over previous
//
#include <hip/hip_runtime.h>
#include <math.h>

#define NPTS 4096
#define DIM 64
#define NM ((size_t)NPTS * (size_t)NPTS)
#define LOGW (-8.317766166719343f)   // -log(4096)
#define NEGINF (-__builtin_inff())

typedef __bf16 bf16x8 __attribute__((ext_vector_type(8)));
typedef float f32x4 __attribute__((ext_vector_type(4)));
typedef _Float16 half8 __attribute__((ext_vector_type(8)));

static __device__ __forceinline__ f32x4 mfma16(bf16x8 a, bf16x8 b, f32x4 c) {
  return __builtin_amdgcn_mfma_f32_16x16x32_bf16(a, b, c, 0, 0, 0);
}

// ---------------------------------------------------------------------------
// Normalize rows to unit L2 norm and split into bf16 hi/lo pairs
// (v = hi + lo with |lo| <= 2^-9 |v| -> split-bf16 GEMM gives ~fp32 accuracy).
// One wave per row; grid 2048 x 256 covers 8192 rows (x then y).
// ---------------------------------------------------------------------------
__global__ __launch_bounds__(256) void norm_split_kernel(
    const float* __restrict__ x, const float* __restrict__ y,
    __bf16* __restrict__ xh, __bf16* __restrict__ xl,
    __bf16* __restrict__ yh, __bf16* __restrict__ yl) {
  int row  = blockIdx.x * 4 + (threadIdx.x >> 6);
  int lane = threadIdx.x & 63;
  const float* src; __bf16 *dh, *dl;
  if (row < NPTS) {
    src = x + (size_t)row * DIM; dh = xh + (size_t)row * DIM; dl = xl + (size_t)row * DIM;
  } else {
    int r = row - NPTS;
    src = y + (size_t)r * DIM; dh = yh + (size_t)r * DIM; dl = yl + (size_t)r * DIM;
  }
  float v = src[lane];
  float s = v * v;
  #pragma unroll
  for (int o = 32; o; o >>= 1) s += __shfl_xor(s, o, 64);
  v *= 1.0f / sqrtf(s);
  __bf16 h = (__bf16)v;
  __bf16 l = (__bf16)(v - (float)h);
  dh[lane] = h;
  dl[lane] = l;
}

// ---------------------------------------------------------------------------
// Cost matrices via split-bf16 MFMA: C = max(1 - A.B^T, 0), stored fp16.
// blockIdx.z: 0 -> Cxy (x,y), 1 -> Cyx (y,x), 2 -> Cxx, 3 -> Cyy.
// 64x64 tile / block, 4 waves; wave w does rows [w*16, w*16+16), 4 col-tiles.
// dot = hi.hi + lo.hi + hi.lo  (lo.lo ~ 2^-18, dropped). 6 MFMA per 16x16 tile.
// A-frag: lane L holds A[m = L&15][k = (L>>4)*8 + j]; B identical (B^T GEMM).
// C/D: col = L&15, row = (L>>4)*4 + reg.
// ---------------------------------------------------------------------------
__global__ __launch_bounds__(256) void cost_mfma_kernel(
    const __bf16* __restrict__ xh, const __bf16* __restrict__ xl,
    const __bf16* __restrict__ yh, const __bf16* __restrict__ yl,
    _Float16* __restrict__ Cw) {
  int mat = blockIdx.z;
  const __bf16 *Ah, *Al, *Bh, *Bl;
  if (mat == 0)      { Ah = xh; Al = xl; Bh = yh; Bl = yl; }
  else if (mat == 1) { Ah = yh; Al = yl; Bh = xh; Bl = xl; }
  else if (mat == 2) { Ah = xh; Al = xl; Bh = xh; Bl = xl; }
  else               { Ah = yh; Al = yl; Bh = yh; Bl = yl; }
  _Float16* Cout = Cw + (size_t)mat * NM;

  int i0 = blockIdx.y * 64, j0 = blockIdx.x * 64;
  int wave = threadIdx.x >> 6, L = threadIdx.x & 63;
  int mrow = L & 15, quad = L >> 4;

  size_t abase = (size_t)(i0 + wave * 16 + mrow) * DIM + quad * 8;
  bf16x8 ah0 = *(const bf16x8*)(Ah + abase);
  bf16x8 ah1 = *(const bf16x8*)(Ah + abase + 32);
  bf16x8 al0 = *(const bf16x8*)(Al + abase);
  bf16x8 al1 = *(const bf16x8*)(Al + abase + 32);

  #pragma unroll
  for (int ct = 0; ct < 4; ++ct) {
    size_t bbase = (size_t)(j0 + ct * 16 + mrow) * DIM + quad * 8;
    bf16x8 bh0 = *(const bf16x8*)(Bh + bbase);
    bf16x8 bh1 = *(const bf16x8*)(Bh + bbase + 32);
    bf16x8 bl0 = *(const bf16x8*)(Bl + bbase);
    bf16x8 bl1 = *(const bf16x8*)(Bl + bbase + 32);
    f32x4 acc = {0.0f, 0.0f, 0.0f, 0.0f};
    acc = mfma16(ah0, bh0, acc);
    acc = mfma16(ah1, bh1, acc);
    acc = mfma16(al0, bh0, acc);
    acc = mfma16(al1, bh1, acc);
    acc = mfma16(ah0, bl0, acc);
    acc = mfma16(ah1, bl1, acc);
    int gj = j0 + ct * 16 + mrow;
    #pragma unroll
    for (int q = 0; q < 4; ++q) {
      int gi = i0 + wave * 16 + quad * 4 + q;
      Cout[(size_t)gi * NPTS + gj] = (_Float16)fmaxf(1.0f - acc[q], 0.0f);
    }
  }
}

// ---------------------------------------------------------------------------
// One sweep: 4 row-softmins over the 4 fp16 matrices, with the 0.5-average
// update fused (ping-pong potOld -> potNew; no separate update kernel).
//   mat 0: Cxy rows  -> ft_ba, h from g_ab  (reads pot[1], writes pot[0])
//   mat 1: Cyx rows  -> gt_ab, h from f_ba  (reads pot[0], writes pot[1])
//   mat 2: Cxx rows  -> ft_aa, h from f_aa  (reads/writes pot[2])
//   mat 3: Cyy rows  -> gt_bb, h from g_bb  (reads/writes pot[3])
// Online max-shifted logsumexp, dual accumulators to shorten the dep chain.
// Grid 4096 blocks (4 mats x 1024), 4 rows/block (one wave per row).
// ---------------------------------------------------------------------------
__global__ __launch_bounds__(256) void pass_kernel(
    const _Float16* __restrict__ Cw,
    const float* __restrict__ potOld, float* __restrict__ potNew,
    float inv_eps, float eps, int use_pot, int avg) {
  int blk  = blockIdx.x;
  int mat  = blk >> 10;
  int row  = (blk & 1023) * 4 + (threadIdx.x >> 6);
  int lane = threadIdx.x & 63;
  const _Float16* Crow = Cw + (size_t)mat * NM + (size_t)row * NPTS;
  int ridx = (mat == 0) ? 1 : ((mat == 1) ? 0 : mat);
  const float* pot = potOld + (size_t)ridx * NPTS;

  float m0 = NEGINF, s0 = 0.0f, m1 = NEGINF, s1 = 0.0f;
  #pragma unroll 2
  for (int t = 0; t < 8; ++t) {
    int j = lane * 8 + t * 512;
    half8 c8 = *(const half8*)(Crow + j);
    float h[8];
    if (use_pot) {
      float4 pa = *(const float4*)(pot + j);
      float4 pb = *(const float4*)(pot + j + 4);
      h[0] = fmaf(pa.x, inv_eps, LOGW); h[1] = fmaf(pa.y, inv_eps, LOGW);
      h[2] = fmaf(pa.z, inv_eps, LOGW); h[3] = fmaf(pa.w, inv_eps, LOGW);
      h[4] = fmaf(pb.x, inv_eps, LOGW); h[5] = fmaf(pb.y, inv_eps, LOGW);
      h[6] = fmaf(pb.z, inv_eps, LOGW); h[7] = fmaf(pb.w, inv_eps, LOGW);
    } else {
      #pragma unroll
      for (int e = 0; e < 8; ++e) h[e] = LOGW;
    }
    #pragma unroll
    for (int e = 0; e < 8; e += 2) {
      float tv = fmaf((float)c8[e], -inv_eps, h[e]);
      float mn = fmaxf(m0, tv);
      s0 = s0 * __expf(m0 - mn) + __expf(tv - mn);
      m0 = mn;
      float tv1 = fmaf((float)c8[e + 1], -inv_eps, h[e + 1]);
      float mn1 = fmaxf(m1, tv1);
      s1 = s1 * __expf(m1 - mn1) + __expf(tv1 - mn1);
      m1 = mn1;
    }
  }
  // merge dual accumulators
  {
    float mn = fmaxf(m0, m1);
    s0 = s0 * __expf(m0 - mn) + s1 * __expf(m1 - mn);
    m0 = mn;
  }
  // wave merge of (m, s)
  #pragma unroll
  for (int o = 1; o < 64; o <<= 1) {
    float m2 = __shfl_xor(m0, o, 64);
    float s2 = __shfl_xor(s0, o, 64);
    float mn = fmaxf(m0, m2);
    s0 = s0 * __expf(m0 - mn) + s2 * __expf(m2 - mn);
    m0 = mn;
  }
  if (lane == 0) {
    float ft = -eps * (m0 + __logf(s0));
    float v = avg ? 0.5f * (potOld[(size_t)mat * NPTS + row] + ft) : ft;
    potNew[(size_t)mat * NPTS + row] = v;
  }
}

// ---------------------------------------------------------------------------
// out = mean(f_ba - f_aa) + mean(g_ab - g_bb), potentials at pot[0..3][NPTS]
// ---------------------------------------------------------------------------
__global__ __launch_bounds__(256) void final_kernel(
    const float* __restrict__ pot, float* __restrict__ out) {
  __shared__ float red[256];
  float s = 0.0f;
  for (int j = threadIdx.x; j < NPTS; j += 256)
    s += (pot[j] - pot[2 * NPTS + j]) + (pot[NPTS + j] - pot[3 * NPTS + j]);
  red[threadIdx.x] = s;
  __syncthreads();
  #pragma unroll
  for (int o = 128; o; o >>= 1) {
    if (threadIdx.x < o) red[threadIdx.x] += red[threadIdx.x + o];
    __syncthreads();
  }
  if (threadIdx.x == 0) out[0] = red[0] / (float)NPTS;
}

extern "C" void kernel_launch(void* const* d_in, const int* in_sizes, int n_in,
                              void* d_out, int out_size, void* d_ws, size_t ws_size,
                              hipStream_t stream) {
  const float* x = (const float*)d_in[0];
  const float* y = (const float*)d_in[1];
  char* ws = (char*)d_ws;

  // workspace layout
  _Float16* Cw = (_Float16*)ws;                       // 4 * NM fp16 = 128 MB
  __bf16* xh = (__bf16*)(ws + 4 * NM * sizeof(_Float16));
  __bf16* xl = xh + (size_t)NPTS * DIM;
  __bf16* yh = xl + (size_t)NPTS * DIM;
  __bf16* yl = yh + (size_t)NPTS * DIM;
  float* potA = (float*)(yl + (size_t)NPTS * DIM);    // 4 * NPTS
  float* potB = potA + 4 * (size_t)NPTS;
  size_t needed = (size_t)((char*)(potB + 4 * (size_t)NPTS) - ws);
  if (ws_size < needed) return;

  norm_split_kernel<<<2048, 256, 0, stream>>>(x, y, xh, xl, yh, yl);
  cost_mfma_kernel<<<dim3(64, 64, 4), 256, 0, stream>>>(xh, xl, yh, yl, Cw);

  // geomloss epsilon schedule (p=2, blur=0.05, scaling=0.8, diameter=2)
  double lst[32];
  int c = 0;
  lst[c++] = 4.0;
  double start = 2.0 * log(2.0), stop = 2.0 * log(0.05), step = 2.0 * log(0.8);
  for (int k = 0;; ++k) {
    double v = start + (double)k * step;
    if (v <= stop) break;
    lst[c++] = exp(v);
  }
  lst[c++] = 0.05 * 0.05;   // c == 19

  // sweeps: p=0 init (no pot, assign); p=1..c loop (avg); p=c+1 final (assign)
  for (int p = 0; p < c + 2; ++p) {
    double e = (p == 0) ? lst[0] : ((p <= c) ? lst[p - 1] : lst[c - 1]);
    float eps = (float)e;
    float inv_eps = 1.0f / eps;
    int use_pot = (p > 0) ? 1 : 0;
    int avg = (p >= 1 && p <= c) ? 1 : 0;
    const float* po = (p & 1) ? potB : potA;
    float* pn       = (p & 1) ? potA : potB;
    pass_kernel<<<4096, 256, 0, stream>>>(Cw, po, pn, inv_eps, eps, use_pot, avg);
  }
  // c+2 = 21 sweeps; last sweep (p=20, even) wrote potB
  final_kernel<<<1, 256, 0, stream>>>(potB, (float*)d_out);
}